// Round 6
// baseline (129.774 us; speedup 1.0000x reference)
//
#include <hip/hip_runtime.h>
#include <hip/hip_fp16.h>
#include <math.h>

#define KDIM 256
#define NITER 50

// One block per batch. 1024 threads = 16 waves. ~135 KB LDS -> 1 block/CU.
// C[b] staged to LDS as fp16 with col XOR (row&63) swizzle:
//   element (r,c) lives at Ch[r*256 + (c ^ (r&63))]
// FW column gather (fixed c, rows r=lane+64k): addr swizzle = c^lane -> 2-way banks (free).
__global__ __launch_bounds__(1024, 1) void cacis_one(
    const float* __restrict__ scores, const int* __restrict__ targets,
    const float* __restrict__ C, float* __restrict__ lossB)
{
    const int b = blockIdx.x;
    const int tid = threadIdx.x, lane = tid & 63, wave = tid >> 6;  // 16 waves
    const float4* C4 = (const float4*)(C + (size_t)b * KDIM * KDIM);

    __shared__ __half Ch[KDIM*KDIM];     // 128 KB
    __shared__ float sf[KDIM];
    __shared__ float rs[KDIM];
    __shared__ float aAll[KDIM];
    __shared__ float wS[16], wT[16], wM[16];
    __shared__ float bc2[2];
    __shared__ int   wcnt[16];
    __shared__ int   sIdx[64];
    __shared__ float sLog[64];
    __shared__ float wm[16], wsm[16];

    if (tid < KDIM) sf[tid] = 0.5f * scores[b*KDIM + tid];
    __syncthreads();

    const int c0 = lane * 4;
    const float fj0 = sf[c0], fj1 = sf[c0+1], fj2 = sf[c0+2], fj3 = sf[c0+3];

    // ---------- pass 1: stream C[b] once (HBM), exact fp32 partials, stage fp16 to LDS ----------
    float psum = 0.f, ptrace = 0.f, pmin = INFINITY;
    #pragma unroll
    for (int rr = 0; rr < 16; ++rr) {
        const int row = rr*16 + wave;
        float4 c4 = C4[row*(KDIM/4) + lane];
        const float frow = sf[row];
        psum += (c4.x + c4.y) + (c4.z + c4.w);
        pmin = fminf(pmin, fminf(fminf(frow+fj0+c4.x, frow+fj1+c4.y),
                                 fminf(frow+fj2+c4.z, frow+fj3+c4.w)));
        if ((row >> 2) == lane) {
            int r2 = row & 3;
            ptrace += (r2==0) ? c4.x : (r2==1) ? c4.y : (r2==2) ? c4.z : c4.w;
        }
        const int rbase = row * KDIM;
        const int sw = row & 63;
        Ch[rbase + ((c0  ) ^ sw)] = __float2half(c4.x);
        Ch[rbase + ((c0+1) ^ sw)] = __float2half(c4.y);
        Ch[rbase + ((c0+2) ^ sw)] = __float2half(c4.z);
        Ch[rbase + ((c0+3) ^ sw)] = __float2half(c4.w);
    }
    #pragma unroll
    for (int off = 32; off > 0; off >>= 1) {
        psum   += __shfl_xor(psum, off);
        ptrace += __shfl_xor(ptrace, off);
        pmin    = fminf(pmin, __shfl_xor(pmin, off));
    }
    if (lane == 0) { wS[wave] = psum; wT[wave] = ptrace; wM[wave] = pmin; }
    __syncthreads();
    if (tid == 0) {
        float s = 0.f, t = 0.f, mn = INFINITY;
        #pragma unroll
        for (int w = 0; w < 16; ++w) { s += wS[w]; t += wT[w]; mn = fminf(mn, wM[w]); }
        bc2[0] = mn;
        bc2[1] = fmaxf((s - t) / (float)(KDIM*KDIM - KDIM), 1e-8f);
    }
    __syncthreads();
    const float minv = bc2[0];
    const float eps = bc2[1];
    const float inv_eps = 1.0f / eps;

    // ---------- rowsums of M from LDS fp16 ----------
    #pragma unroll
    for (int rr = 0; rr < 16; ++rr) {
        const int row = rr*16 + wave;
        const float frow = sf[row];
        const int rbase = row * KDIM;
        const int sw = row & 63;
        const float x0 = __half2float(Ch[rbase + ((c0  ) ^ sw)]);
        const float x1 = __half2float(Ch[rbase + ((c0+1) ^ sw)]);
        const float x2 = __half2float(Ch[rbase + ((c0+2) ^ sw)]);
        const float x3 = __half2float(Ch[rbase + ((c0+3) ^ sw)]);
        float p = __expf((minv - (frow+fj0+x0)) * inv_eps)
                + __expf((minv - (frow+fj1+x1)) * inv_eps)
                + __expf((minv - (frow+fj2+x2)) * inv_eps)
                + __expf((minv - (frow+fj3+x3)) * inv_eps);
        #pragma unroll
        for (int off = 32; off > 0; off >>= 1) p += __shfl_xor(p, off);
        if (lane == 0) rs[row] = p;
    }
    __syncthreads();

    // ---------- FW on wave 0: lane owns rows {lane, lane+64, lane+128, lane+192} ----------
    if (wave == 0) {
        const float f0 = sf[lane], f1 = sf[lane+64], f2 = sf[lane+128], f3 = sf[lane+192];
        const int base0 = lane*KDIM, base1 = (lane+64)*KDIM, base2 = (lane+128)*KDIM, base3 = (lane+192)*KDIM;

        // argmin of rowsum (grad0 direction), lowest-index tiebreak
        float v = rs[lane]; int vi = lane;
        float t;
        t = rs[lane+64];  if (t < v) { v = t; vi = lane+64; }
        t = rs[lane+128]; if (t < v) { v = t; vi = lane+128; }
        t = rs[lane+192]; if (t < v) { v = t; vi = lane+192; }
        #pragma unroll
        for (int off = 32; off > 0; off >>= 1) {
            float ov = __shfl_xor(v, off);
            int  ovi = __shfl_xor(vi, off);
            if (ov < v || (ov == v && ovi < vi)) { v = ov; vi = ovi; }
        }
        const int idx0 = vi;

        const float fidx0 = sf[idx0];
        int sc = idx0 ^ lane;
        float g0 = 2.0f * __expf((minv - (f0 + fidx0 + __half2float(Ch[base0 + sc]))) * inv_eps);
        float g1 = 2.0f * __expf((minv - (f1 + fidx0 + __half2float(Ch[base1 + sc]))) * inv_eps);
        float g2 = 2.0f * __expf((minv - (f2 + fidx0 + __half2float(Ch[base2 + sc]))) * inv_eps);
        float g3 = 2.0f * __expf((minv - (f3 + fidx0 + __half2float(Ch[base3 + sc]))) * inv_eps);
        float a0 = (lane     == idx0) ? 1.0f : 0.0f;
        float a1 = (lane+64  == idx0) ? 1.0f : 0.0f;
        float a2 = (lane+128 == idx0) ? 1.0f : 0.0f;
        float a3 = (lane+192 == idx0) ? 1.0f : 0.0f;

        for (int it = 1; it < NITER; ++it) {
            float v2 = g0; int vi2 = lane;
            if (g1 < v2) { v2 = g1; vi2 = lane+64; }
            if (g2 < v2) { v2 = g2; vi2 = lane+128; }
            if (g3 < v2) { v2 = g3; vi2 = lane+192; }
            #pragma unroll
            for (int off = 32; off > 0; off >>= 1) {
                float ov = __shfl_xor(v2, off);
                int  ovi = __shfl_xor(vi2, off);
                if (ov < v2 || (ov == v2 && ovi < vi2)) { v2 = ov; vi2 = ovi; }
            }
            const int idx = vi2;
            const float gamma = 2.0f / ((float)it + 2.0f);
            const float omg = 1.0f - gamma;
            const int which = idx >> 6;
            float fsel = (which==0) ? f0 : (which==1) ? f1 : (which==2) ? f2 : f3;
            const float fidx = __shfl(fsel, idx & 63);
            sc = idx ^ lane;
            const float cc0 = __half2float(Ch[base0 + sc]);
            const float cc1 = __half2float(Ch[base1 + sc]);
            const float cc2 = __half2float(Ch[base2 + sc]);
            const float cc3 = __half2float(Ch[base3 + sc]);
            g0 = omg*g0 + 2.0f*gamma*__expf((minv - (f0 + fidx + cc0)) * inv_eps);
            g1 = omg*g1 + 2.0f*gamma*__expf((minv - (f1 + fidx + cc1)) * inv_eps);
            g2 = omg*g2 + 2.0f*gamma*__expf((minv - (f2 + fidx + cc2)) * inv_eps);
            g3 = omg*g3 + 2.0f*gamma*__expf((minv - (f3 + fidx + cc3)) * inv_eps);
            a0 = omg*a0 + ((lane     == idx) ? gamma : 0.0f);
            a1 = omg*a1 + ((lane+64  == idx) ? gamma : 0.0f);
            a2 = omg*a2 + ((lane+128 == idx) ? gamma : 0.0f);
            a3 = omg*a3 + ((lane+192 == idx) ? gamma : 0.0f);
        }
        aAll[lane]     = a0;
        aAll[lane+64]  = a1;
        aAll[lane+128] = a2;
        aAll[lane+192] = a3;
    }
    __syncthreads();

    const float a = (tid < KDIM) ? aAll[tid] : 0.f;

    // ---------- support collection via ballot compaction (<=50, tid-ordered) ----------
    unsigned long long mask = __ballot(a > 0.f);
    if (lane == 0) wcnt[wave] = __popcll(mask);
    __syncthreads();
    int off0 = 0;
    for (int w = 0; w < wave; ++w) off0 += wcnt[w];
    int count = 0;
    #pragma unroll
    for (int w = 0; w < 16; ++w) count += wcnt[w];
    if (a > 0.f) {
        int pos = off0 + __popcll(mask & ((1ull << lane) - 1ull));
        sIdx[pos] = tid;
        sLog[pos] = logf(a);
    }
    __syncthreads();

    // ---------- logsumexp over support pairs from LDS fp16 ----------
    float m = -INFINITY, ss = 0.f;
    const int total = count * count;
    for (int p = tid; p < total; p += 1024) {
        int ii = p / count;
        int jj = p - ii * count;
        int i = sIdx[ii], j = sIdx[jj];
        float cij = __half2float(Ch[i*KDIM + (j ^ (i & 63))]);
        float lm = (minv - (sf[i] + sf[j] + cij)) * inv_eps;
        float tt = sLog[ii] + sLog[jj] + lm;
        if (tt > m) { ss = ss * __expf(m - tt) + 1.0f; m = tt; }
        else        { ss += __expf(tt - m); }
    }
    #pragma unroll
    for (int off = 32; off > 0; off >>= 1) {
        float om = __shfl_xor(m, off);
        float os = __shfl_xor(ss, off);
        if (os > 0.f) {
            if (ss <= 0.f)   { m = om; ss = os; }
            else if (om > m) { ss = ss*__expf(m-om) + os; m = om; }
            else             { ss += os*__expf(om-m); }
        }
    }
    if (lane == 0) { wm[wave] = m; wsm[wave] = ss; }
    __syncthreads();
    if (tid == 0) {
        float M = wm[0], S = wsm[0];
        #pragma unroll
        for (int w = 1; w < 16; ++w) {
            float om = wm[w], os = wsm[w];
            if (os > 0.f) {
                if (S <= 0.f)    { M = om; S = os; }
                else if (om > M) { S = S*__expf(M-om) + os; M = om; }
                else             { S += os*__expf(om-M); }
            }
        }
        float logval = M + logf(S);
        float shift = -minv * inv_eps;
        float conjugate = -eps * (logval + shift);
        float fy = scores[b*KDIM + targets[b]];
        lossB[b] = conjugate - fy;
    }
}

__global__ __launch_bounds__(512) void cacis_reduce(const float* __restrict__ lossB,
                                                    float* __restrict__ out, int B)
{
    __shared__ float red[512];
    int t = threadIdx.x;
    red[t] = (t < B) ? lossB[t] : 0.f;
    __syncthreads();
    for (int s = 256; s > 0; s >>= 1) { if (t < s) red[t] += red[t+s]; __syncthreads(); }
    if (t == 0) out[0] = red[0] / (float)B;
}

extern "C" void kernel_launch(void* const* d_in, const int* in_sizes, int n_in,
                              void* d_out, int out_size, void* d_ws, size_t ws_size,
                              hipStream_t stream) {
    const float* scores  = (const float*)d_in[0];
    const int*   targets = (const int*)d_in[1];
    const float* C       = (const float*)d_in[2];
    float* out = (float*)d_out;
    const int B = in_sizes[1];   // 512

    float* lossB = (float*)d_ws;

    cacis_one  <<<B, 1024, 0, stream>>>(scores, targets, C, lossB);
    cacis_reduce<<<1, 512, 0, stream>>>(lossB, out, B);
}